// Round 1
// baseline (1040.732 us; speedup 1.0000x reference)
//
#include <hip/hip_runtime.h>

typedef __bf16 bf16x8 __attribute__((ext_vector_type(8)));
typedef float f32x16 __attribute__((ext_vector_type(16)));
typedef unsigned int u32x4 __attribute__((ext_vector_type(4)));

#define NGROUP 8
#define DMODEL 256
#define DFF    1024
#define TTOT   131072
#define TGRP   (TTOT / NGROUP)   // 16384
#define MTILE  128
#define NCHUNK (DFF / 64)        // 16
#define HPITCH 72                // h LDS pitch (64 + 8 pad, keeps 16B align)

__device__ __forceinline__ unsigned int f2bf(float f) {
    unsigned int x = __builtin_bit_cast(unsigned int, f);
    return (x + 0x7fffu + ((x >> 16) & 1u)) >> 16;   // RNE
}
__device__ __forceinline__ unsigned int pack2(float lo, float hi) {
    return f2bf(lo) | (f2bf(hi) << 16);
}

// ---------------- prep: x fp32 -> bf16 row-major ----------------
__global__ void k_cvt_x(const float4* __restrict__ in, u32x4* __restrict__ out) {
    int t = blockIdx.x * 256 + threadIdx.x;
    float4 a = in[2 * t];
    float4 b = in[2 * t + 1];
    u32x4 v = { pack2(a.x, a.y), pack2(a.z, a.w), pack2(b.x, b.y), pack2(b.z, b.w) };
    out[t] = v;
}

// ---------------- prep: weight swizzle to 32x32x16 operand frags ----------------
// out[(((g*MB + mb)*KS + ks)*64 + l)][j] = in[(g*K + ks*16 + (l>>5)*8 + j)*N + mb*32 + (l&31)]
// gate/up : K=256 (d), N=1024 (f), MB=32, KS=16  -> A operand of z^T = W^T x^T
// down    : K=1024 (f), N=256 (d), MB=8,  KS=64  -> B operand of y = h Wd
__global__ void k_swz_w(const float* __restrict__ in, u32x4* __restrict__ out,
                        int K, int N, int MB, int KS) {
    int t = blockIdx.x * 256 + threadIdx.x;
    int l = t & 63;
    int rest = t >> 6;
    int ks = rest % KS; rest /= KS;
    int mb = rest % MB;
    int g  = rest / MB;
    const float* p = in + (size_t)(g * K + ks * 16 + (l >> 5) * 8) * N + mb * 32 + (l & 31);
    size_t sN = (size_t)N;
    u32x4 v = { pack2(p[0],      p[sN]),
                pack2(p[2 * sN], p[3 * sN]),
                pack2(p[4 * sN], p[5 * sN]),
                pack2(p[6 * sN], p[7 * sN]) };
    out[t] = v;
}

// ---------------- main fused grouped-GLU ----------------
// block: 512 thr (8 waves), 128 tokens. wave = (fi = w>>2 in 0..1, ti = w&3).
// GEMM1: z^T chunk (64 f x 128 tok), A = W^T frags (global swz), B = x frags (regs).
//   C layout gives 4 consecutive f per reg-quad -> packed b64 h writes to LDS.
// GEMM2: y += h(128 x 64) * Wd chunk, A = h (LDS b128), B = Wd frags (global swz).
__global__ __launch_bounds__(512, 2)
void k_glu(const u32x4* __restrict__ xb,   // bf16 x row-major [T][256]
           const u32x4* __restrict__ gsw,
           const u32x4* __restrict__ usw,
           const u32x4* __restrict__ dsw,
           float* __restrict__ y) {
    __shared__ unsigned short hs[MTILE * HPITCH];   // 18432 B

    const int tid  = threadIdx.x;
    const int lane = tid & 63;
    const int w    = tid >> 6;
    const int q    = lane >> 5;
    const int l31  = lane & 31;
    const int ti   = w & 3;     // token-32 block
    const int fi   = w >> 2;    // 0..1: f-half (GEMM1) / col-half (GEMM2)

    const int g    = blockIdx.x >> 7;
    const int m0   = g * TGRP + (blockIdx.x & 127) * MTILE;
    const int tokw = ti * 32 + l31;

    // x fragments into registers: xf[ks] = x[m0+tokw][ks*16 + q*8 .. +8]
    u32x4 xf[16];
    {
        const u32x4* xrow = xb + (size_t)(m0 + tokw) * 32 + q;
        #pragma unroll
        for (int ks = 0; ks < 16; ++ks) xf[ks] = xrow[ks * 2];
    }

    f32x16 acc[4];
    #pragma unroll
    for (int nb = 0; nb < 4; ++nb) {
        #pragma unroll
        for (int i = 0; i < 16; ++i) acc[nb][i] = 0.0f;
    }

    const u32x4* ag = gsw + (((size_t)((g * 32 + fi) * 16)) << 6) + lane;
    const u32x4* au = usw + (((size_t)((g * 32 + fi) * 16)) << 6) + lane;
    const u32x4* ad = dsw + (((size_t)((g * 8 + fi * 4) * 64)) << 6) + lane;

    for (int c = 0; c < NCHUNK; ++c) {
        f32x16 zg, zu;
        #pragma unroll
        for (int i = 0; i < 16; ++i) { zg[i] = 0.0f; zu[i] = 0.0f; }

        // GEMM1: z^T[f = c*64 + fi*32 + ..][token] over K = 256
        const u32x4* agc = ag + ((size_t)(c * 32) << 6);
        const u32x4* auc = au + ((size_t)(c * 32) << 6);
        #pragma unroll
        for (int ks = 0; ks < 16; ++ks) {
            const u32x4 a1 = agc[(size_t)ks << 6];
            const u32x4 a2 = auc[(size_t)ks << 6];
            zg = __builtin_amdgcn_mfma_f32_32x32x16_bf16(
                     __builtin_bit_cast(bf16x8, a1),
                     __builtin_bit_cast(bf16x8, xf[ks]), zg, 0, 0, 0);
            zu = __builtin_amdgcn_mfma_f32_32x32x16_bf16(
                     __builtin_bit_cast(bf16x8, a2),
                     __builtin_bit_cast(bf16x8, xf[ks]), zu, 0, 0, 0);
        }

        __syncthreads();   // prev chunk's hs fully consumed
        // silu(zg)*zu -> bf16 -> LDS h[token][f_local], packed 4-wide along f
        #pragma unroll
        for (int a = 0; a < 4; ++a) {
            const float g0 = zg[4 * a + 0], g1 = zg[4 * a + 1];
            const float g2 = zg[4 * a + 2], g3 = zg[4 * a + 3];
            const float h0 = g0 / (1.0f + __expf(-g0)) * zu[4 * a + 0];
            const float h1 = g1 / (1.0f + __expf(-g1)) * zu[4 * a + 1];
            const float h2 = g2 / (1.0f + __expf(-g2)) * zu[4 * a + 2];
            const float h3 = g3 / (1.0f + __expf(-g3)) * zu[4 * a + 3];
            uint2 pv;
            pv.x = pack2(h0, h1);
            pv.y = pack2(h2, h3);
            *(uint2*)&hs[tokw * HPITCH + fi * 32 + a * 8 + q * 4] = pv;
        }
        __syncthreads();

        // GEMM2: acc += h(128 x 64-chunk) * Wd(chunk x 256)
        #pragma unroll
        for (int ks2 = 0; ks2 < 4; ++ks2) {
            const u32x4 ha = *(const u32x4*)&hs[tokw * HPITCH + ks2 * 16 + q * 8];
            #pragma unroll
            for (int nb = 0; nb < 4; ++nb) {
                const u32x4 bd = ad[(size_t)(nb * 64 + c * 4 + ks2) << 6];
                acc[nb] = __builtin_amdgcn_mfma_f32_32x32x16_bf16(
                              __builtin_bit_cast(bf16x8, ha),
                              __builtin_bit_cast(bf16x8, bd), acc[nb], 0, 0, 0);
            }
        }
    }

    // epilogue: C layout -> y fp32
    float* yp = y + (size_t)(m0 + ti * 32) * DMODEL;
    #pragma unroll
    for (int nb = 0; nb < 4; ++nb) {
        const int col = (fi * 4 + nb) * 32 + l31;
        #pragma unroll
        for (int r = 0; r < 16; ++r) {
            const int row = (r & 3) + (r >> 2) * 8 + q * 4;
            yp[(size_t)row * DMODEL + col] = acc[nb][r];
        }
    }
}

extern "C" void kernel_launch(void* const* d_in, const int* in_sizes, int n_in,
                              void* d_out, int out_size, void* d_ws, size_t ws_size,
                              hipStream_t stream) {
    const float* x  = (const float*)d_in[0];
    const float* wg = (const float*)d_in[1];
    const float* wu = (const float*)d_in[2];
    const float* wd = (const float*)d_in[3];
    float* y = (float*)d_out;

    // ws layout (u32x4 units): x_bf16 | gate_swz | up_swz | down_swz  (~76 MB)
    u32x4* xb  = (u32x4*)d_ws;          // 131072*256 bf16 = 4194304 u32x4
    u32x4* gsw = xb  + 4194304;         // 8*32*16*64 = 262144
    u32x4* usw = gsw + 262144;
    u32x4* dsw = usw + 262144;          // 8*8*64*64 = 262144

    k_cvt_x<<<dim3(TTOT * DMODEL / 8 / 256), dim3(256), 0, stream>>>((const float4*)x, xb);
    k_swz_w<<<dim3(1024), dim3(256), 0, stream>>>(wg, gsw, 256, 1024, 32, 16);
    k_swz_w<<<dim3(1024), dim3(256), 0, stream>>>(wu, usw, 256, 1024, 32, 16);
    k_swz_w<<<dim3(1024), dim3(256), 0, stream>>>(wd, dsw, 1024, 256, 8, 64);
    k_glu<<<dim3(1024), dim3(512), 0, stream>>>(xb, gsw, usw, dsw, y);
}

// Round 2
// 483.748 us; speedup vs baseline: 2.1514x; 2.1514x over previous
//
#include <hip/hip_runtime.h>

typedef __bf16 bf16x8 __attribute__((ext_vector_type(8)));
typedef float f32x16 __attribute__((ext_vector_type(16)));
typedef unsigned int u32x4 __attribute__((ext_vector_type(4)));

#define NGROUP 8
#define DMODEL 256
#define DFF    1024
#define TTOT   131072
#define TGRP   (TTOT / NGROUP)   // 16384
#define MTILE  256               // tokens per block (8 waves x 32)
#define NCHUNK 32                // f-chunks of 32 (DFF/32)
// LDS map (64 KB static):
//   [    0, 16K)  gate frags  [ks(16)][lane(64)] x 16B
//   [ 16K, 32K)  up   frags  [ks(16)][lane(64)] x 16B
//   [ 32K, 48K)  down frags  [ks2(2)][nb(8)][lane(64)] x 16B
//   [ 48K, 64K)  h, 8 waves x 2KB (32 tok x 64B), XOR-swizzled, wave-private

__device__ __forceinline__ unsigned int f2bf(float f) {
    unsigned int x = __builtin_bit_cast(unsigned int, f);
    return (x + 0x7fffu + ((x >> 16) & 1u)) >> 16;   // RNE
}
__device__ __forceinline__ unsigned int pack2(float lo, float hi) {
    return f2bf(lo) | (f2bf(hi) << 16);
}

__device__ __forceinline__ void g2l(const void* g, void* l) {
    __builtin_amdgcn_global_load_lds(
        (const __attribute__((address_space(1))) unsigned int*)g,
        (__attribute__((address_space(3))) unsigned int*)l, 16, 0, 0);
}

// ---------------- prep: x fp32 -> bf16 row-major ----------------
__global__ void k_cvt_x(const float4* __restrict__ in, u32x4* __restrict__ out) {
    int t = blockIdx.x * 256 + threadIdx.x;
    float4 a = in[2 * t];
    float4 b = in[2 * t + 1];
    u32x4 v = { pack2(a.x, a.y), pack2(a.z, a.w), pack2(b.x, b.y), pack2(b.z, b.w) };
    out[t] = v;
}

// ---------------- prep: all weights -> per-(group,chunk) 48KB frag blocks ----------------
// Per (g,c): 48 frag-groups of [64 lanes x 16B]:
//   fid 0..15  : gate A-frag, ks=fid      W[d=ks*16+q*8+j][f=c*32+l31]
//   fid 16..31 : up   A-frag, ks=fid-16
//   fid 32..47 : down B-frag, ks2=(fid-32)>>3, nb=(fid-32)&7
//                Wd[f=(c*2+ks2)*16+q*8+j][col=nb*32+l31]
__global__ void k_prep_w(const float* __restrict__ wg, const float* __restrict__ wu,
                         const float* __restrict__ wd, u32x4* __restrict__ out) {
    int t = blockIdx.x * 256 + threadIdx.x;   // 786432 total
    int lane = t & 63;
    int q = lane >> 5, l31 = lane & 31;
    int fg = t >> 6;
    int fid = fg % 48;
    int gc  = fg / 48;
    int c = gc & 31, g = gc >> 5;
    const float* src;
    int stride;
    if (fid < 32) {
        const float* w = (fid < 16) ? wg : wu;
        int ks = fid & 15;
        src = w + (size_t)(g * 256 + ks * 16 + q * 8) * 1024 + c * 32 + l31;
        stride = 1024;
    } else {
        int idx = fid - 32;
        int ks2 = idx >> 3, nb = idx & 7;
        src = wd + (size_t)(g * 1024 + (c * 2 + ks2) * 16 + q * 8) * 256 + nb * 32 + l31;
        stride = 256;
    }
    u32x4 v = { pack2(src[0],          src[stride]),
                pack2(src[2 * stride], src[3 * stride]),
                pack2(src[4 * stride], src[5 * stride]),
                pack2(src[6 * stride], src[7 * stride]) };
    out[t] = v;
}

// ---------------- main fused grouped-GLU ----------------
__global__ __launch_bounds__(512, 2)
void k_glu(const u32x4* __restrict__ xb,     // bf16 x row-major [T][256]
           const u32x4* __restrict__ wcomb,  // [g][c][48 frag-groups][64 lanes]
           float* __restrict__ y) {
    __shared__ u32x4 smem[4096];   // 64 KB

    const int tid  = threadIdx.x;
    const int lane = tid & 63;
    const int w    = tid >> 6;      // wave 0..7 = token-32 block
    const int q    = lane >> 5;
    const int l31  = lane & 31;

    // XCD swizzle: group = blockIdx & 7 so each XCD's L2 holds one group's weights
    const int g    = blockIdx.x & 7;
    const int m0   = g * TGRP + (blockIdx.x >> 3) * MTILE;
    const int tokw = w * 32 + l31;

    // x fragments, register-resident for the whole block
    u32x4 xf[16];
    {
        const u32x4* xrow = xb + (size_t)(m0 + tokw) * 32 + q;
        #pragma unroll
        for (int ks = 0; ks < 16; ++ks) xf[ks] = xrow[ks * 2];
    }

    f32x16 acc[8];
    #pragma unroll
    for (int nb = 0; nb < 8; ++nb)
        #pragma unroll
        for (int i = 0; i < 16; ++i) acc[nb][i] = 0.0f;

    const u32x4* wcg = wcomb + (size_t)(g * 32) * 3072;
    const unsigned int sw = ((l31 >> 2) & 3) << 4;        // h XOR swizzle (flips bits 4,5)
    char* hrow = (char*)smem + 49152 + w * 2048 + l31 * 64;

    for (int c = 0; c < NCHUNK; ++c) {
        __syncthreads();   // chunk c-1's stage+h fully consumed
        // stage 48KB: 6 x (wave-uniform LDS base, global base + lane*16)
        {
            const u32x4* gsrc = wcg + (size_t)c * 3072;
            #pragma unroll
            for (int i = 0; i < 6; ++i) {
                int off = i * 512 + w * 64;   // u32x4 index, wave-uniform
                g2l(gsrc + off + lane, smem + off);
            }
        }
        __syncthreads();   // vmcnt(0) drain: staged data visible

        // ---- GEMM1: z^T (32f x 32tok) over K=256, weights from LDS, x from regs
        f32x16 zg, zu;
        #pragma unroll
        for (int i = 0; i < 16; ++i) { zg[i] = 0.0f; zu[i] = 0.0f; }
        #pragma unroll
        for (int ks = 0; ks < 16; ++ks) {
            const u32x4 a1 = smem[ks * 64 + lane];          // gate
            const u32x4 a2 = smem[1024 + ks * 64 + lane];   // up
            zg = __builtin_amdgcn_mfma_f32_32x32x16_bf16(
                     __builtin_bit_cast(bf16x8, a1),
                     __builtin_bit_cast(bf16x8, xf[ks]), zg, 0, 0, 0);
            zu = __builtin_amdgcn_mfma_f32_32x32x16_bf16(
                     __builtin_bit_cast(bf16x8, a2),
                     __builtin_bit_cast(bf16x8, xf[ks]), zu, 0, 0, 0);
        }

        // ---- act: h = silu(zg)*zu -> bf16 -> wave-private LDS (no barrier needed)
        #pragma unroll
        for (int a = 0; a < 4; ++a) {
            const float g0 = zg[4 * a + 0], g1 = zg[4 * a + 1];
            const float g2 = zg[4 * a + 2], g3 = zg[4 * a + 3];
            const float h0 = g0 / (1.0f + __expf(-g0)) * zu[4 * a + 0];
            const float h1 = g1 / (1.0f + __expf(-g1)) * zu[4 * a + 1];
            const float h2 = g2 / (1.0f + __expf(-g2)) * zu[4 * a + 2];
            const float h3 = g3 / (1.0f + __expf(-g3)) * zu[4 * a + 3];
            uint2 pv;
            pv.x = pack2(h0, h1);
            pv.y = pack2(h2, h3);
            *(uint2*)(hrow + ((unsigned)(a * 16 + q * 8) ^ sw)) = pv;
        }

        // ---- GEMM2: acc += h(32tok x 32f) * Wd(32f x 256)
        #pragma unroll
        for (int ks2 = 0; ks2 < 2; ++ks2) {
            const u32x4 ha = *(const u32x4*)(hrow + ((unsigned)(ks2 * 32 + q * 16) ^ sw));
            #pragma unroll
            for (int nb = 0; nb < 8; ++nb) {
                const u32x4 bd = smem[2048 + (ks2 * 8 + nb) * 64 + lane];
                acc[nb] = __builtin_amdgcn_mfma_f32_32x32x16_bf16(
                              __builtin_bit_cast(bf16x8, ha),
                              __builtin_bit_cast(bf16x8, bd), acc[nb], 0, 0, 0);
            }
        }
    }

    // epilogue: C layout -> y fp32
    float* yp = y + (size_t)(m0 + w * 32) * DMODEL;
    #pragma unroll
    for (int nb = 0; nb < 8; ++nb) {
        const int col = nb * 32 + l31;
        #pragma unroll
        for (int r = 0; r < 16; ++r) {
            const int row = (r & 3) + (r >> 2) * 8 + q * 4;
            yp[(size_t)row * DMODEL + col] = acc[nb][r];
        }
    }
}

extern "C" void kernel_launch(void* const* d_in, const int* in_sizes, int n_in,
                              void* d_out, int out_size, void* d_ws, size_t ws_size,
                              hipStream_t stream) {
    const float* x  = (const float*)d_in[0];
    const float* wg = (const float*)d_in[1];
    const float* wu = (const float*)d_in[2];
    const float* wd = (const float*)d_in[3];
    float* y = (float*)d_out;

    // ws: x_bf16 (64MB) | wcomb (12MB)
    u32x4* xb    = (u32x4*)d_ws;         // 131072*256 bf16 = 4194304 u32x4
    u32x4* wcomb = xb + 4194304;         // 8*32*48*64 = 786432 u32x4

    k_cvt_x<<<dim3(TTOT * DMODEL / 8 / 256), dim3(256), 0, stream>>>((const float4*)x, xb);
    k_prep_w<<<dim3(3072), dim3(256), 0, stream>>>(wg, wu, wd, wcomb);
    k_glu<<<dim3(512), dim3(512), 0, stream>>>(xb, wcomb, y);
}